// Round 2
// baseline (1694.446 us; speedup 1.0000x reference)
//
#include <hip/hip_runtime.h>
#include <math.h>

#define N_NODES 10000
#define N_EDGES 160000
#define BATCH 32
#define HLEN 12
#define KORD 25
#define G1 32
#define NCLS 10
#define BH 384   /* BATCH*HLEN */
#define BG 1024  /* BATCH*G1  */

// ---------------- CSR build ----------------
__global__ void deg_kernel(const int* __restrict__ row, int* __restrict__ cnt) {
    int e = blockIdx.x * 256 + threadIdx.x;
    if (e < N_EDGES) atomicAdd(&cnt[row[e]], 1);
}

__global__ void dinv_kernel(const int* __restrict__ cnt, float* __restrict__ dinv) {
    int n = blockIdx.x * 256 + threadIdx.x;
    if (n < N_NODES) {
        int d = cnt[n];
        dinv[n] = (d > 0) ? 1.0f / sqrtf((float)d) : 0.0f;
    }
}

__global__ __launch_bounds__(1024) void scan_kernel(const int* __restrict__ cnt,
                                                    int* __restrict__ rowstart) {
    __shared__ int sums[1024];
    int t = threadIdx.x;
    const int per = 10; // 1024*10 >= 10000
    int base = t * per;
    int s = 0;
    for (int i = 0; i < per; i++) { int idx = base + i; if (idx < N_NODES) s += cnt[idx]; }
    sums[t] = s;
    __syncthreads();
    for (int off = 1; off < 1024; off <<= 1) {
        int v = 0;
        if (t >= off) v = sums[t - off];
        __syncthreads();
        sums[t] += v;
        __syncthreads();
    }
    int run = sums[t] - s; // exclusive prefix for this chunk
    for (int i = 0; i < per; i++) {
        int idx = base + i;
        if (idx < N_NODES) { rowstart[idx] = run; run += cnt[idx]; }
    }
    if (t == 1023) rowstart[N_NODES] = run;
}

__global__ void scatter_kernel(const int* __restrict__ row, const int* __restrict__ col,
                               const float* __restrict__ dinv,
                               const int* __restrict__ rowstart, int* __restrict__ cursor,
                               int* __restrict__ csr_col, float* __restrict__ csr_norm) {
    int e = blockIdx.x * 256 + threadIdx.x;
    if (e < N_EDGES) {
        int r = row[e], c = col[e];
        int p = rowstart[r] + atomicAdd(&cursor[r], 1);
        csr_col[p] = c;
        csr_norm[p] = -dinv[r] * dinv[c];
    }
}

// ---------------- FFT (real part, H=12 cosine transform) ----------------
// x: [B, N, H] b-major.  xf: [N, B*H] node-major.
__global__ __launch_bounds__(256) void fft_kernel(const float* __restrict__ x,
                                                  float* __restrict__ xf) {
    __shared__ float C[HLEN][HLEN];
    int t = threadIdx.x;
    if (t < HLEN * HLEN) {
        int k = t / HLEN, tt = t % HLEN;
        C[k][tt] = cosf(0.52359877559829887308f * (float)(k * tt)); // pi/6 * k*t
    }
    __syncthreads();
    int tid = blockIdx.x * 256 + t; // tid = n*32 + b
    if (tid >= N_NODES * BATCH) return;
    int n = tid >> 5, b = tid & 31;
    const float* xp = x + (size_t)b * (N_NODES * HLEN) + (size_t)n * HLEN;
    float xr[HLEN];
#pragma unroll
    for (int i = 0; i < HLEN; i++) xr[i] = xp[i];
    float* o = xf + (size_t)n * BH + b * HLEN;
#pragma unroll
    for (int k = 0; k < HLEN; k++) {
        float s = 0.f;
#pragma unroll
        for (int i = 0; i < HLEN; i++) s += xr[i] * C[k][i];
        o[k] = s;
    }
}

// ---------------- k=0 einsum (initializes out) ----------------
__global__ __launch_bounds__(256) void k0_kernel(const float* __restrict__ z,
                                                 float* __restrict__ out,
                                                 const float* __restrict__ w0) {
    __shared__ __align__(16) float lds[4][BH];
    __shared__ float wk[BH];
    int t = threadIdx.x;
    for (int i = t; i < BH; i += 256) wk[i] = w0[i];
    int wv = t >> 6, lane = t & 63;
    int node = blockIdx.x * 4 + wv;
    const float* zp = z + (size_t)node * BH;
    float4 z4 = *(const float4*)(zp + 4 * lane);
    float2 z2 = *(const float2*)(zp + 256 + 2 * lane);
    *(float4*)(&lds[wv][4 * lane]) = z4;
    *(float2*)(&lds[wv][256 + 2 * lane]) = z2;
    __syncthreads();
    float* op = out + (size_t)node * BG;
#pragma unroll
    for (int r = 0; r < 4; r++) {
        int idx = 4 * lane + 256 * r;
        int b = idx >> 5;
        int f0 = idx & 31;
        const float* zb = &lds[wv][b * HLEN];
        float4 s = {0.f, 0.f, 0.f, 0.f};
#pragma unroll
        for (int h = 0; h < HLEN; h++) {
            float zv = zb[h];
            s.x += zv * wk[h * G1 + f0 + 0];
            s.y += zv * wk[h * G1 + f0 + 1];
            s.z += zv * wk[h * G1 + f0 + 2];
            s.w += zv * wk[h * G1 + f0 + 3];
        }
        *(float4*)(op + idx) = s;
    }
}

// ---------------- fused prop + einsum accumulate ----------------
// tx_next = alpha * (Lt @ z_cur) - beta * z_prev ; out += tx_next @ Wk
// znext may alias zprev (each element read before written, by its own thread).
__global__ __launch_bounds__(256) void prop_kernel(
    const float* __restrict__ zcur, const float* __restrict__ zprev,
    float* __restrict__ znext, float* __restrict__ out,
    const int* __restrict__ rowstart, const int* __restrict__ csr_col,
    const float* __restrict__ csr_norm, const float* __restrict__ wkg,
    float alpha, float beta) {
    __shared__ __align__(16) float lds[4][BH];
    __shared__ float wk[BH];
    int t = threadIdx.x;
    for (int i = t; i < BH; i += 256) wk[i] = wkg[i];
    int wv = t >> 6, lane = t & 63;
    int node = blockIdx.x * 4 + wv;

    float4 a4 = {0.f, 0.f, 0.f, 0.f};
    float2 a2 = {0.f, 0.f};
    int e0 = rowstart[node], e1 = rowstart[node + 1];
    for (int e = e0; e < e1; e++) {
        int c = csr_col[e];
        float nrm = csr_norm[e];
        const float* zp = zcur + (size_t)c * BH;
        float4 z4 = *(const float4*)(zp + 4 * lane);
        float2 z2 = *(const float2*)(zp + 256 + 2 * lane);
        a4.x += nrm * z4.x; a4.y += nrm * z4.y;
        a4.z += nrm * z4.z; a4.w += nrm * z4.w;
        a2.x += nrm * z2.x; a2.y += nrm * z2.y;
    }
    const float* pv = zprev + (size_t)node * BH;
    float4 p4 = *(const float4*)(pv + 4 * lane);
    float2 p2 = *(const float2*)(pv + 256 + 2 * lane);
    float4 v4; float2 v2;
    v4.x = alpha * a4.x - beta * p4.x;
    v4.y = alpha * a4.y - beta * p4.y;
    v4.z = alpha * a4.z - beta * p4.z;
    v4.w = alpha * a4.w - beta * p4.w;
    v2.x = alpha * a2.x - beta * p2.x;
    v2.y = alpha * a2.y - beta * p2.y;
    float* nx = znext + (size_t)node * BH;
    *(float4*)(nx + 4 * lane) = v4;
    *(float2*)(nx + 256 + 2 * lane) = v2;
    *(float4*)(&lds[wv][4 * lane]) = v4;
    *(float2*)(&lds[wv][256 + 2 * lane]) = v2;
    __syncthreads();
    float* op = out + (size_t)node * BG;
#pragma unroll
    for (int r = 0; r < 4; r++) {
        int idx = 4 * lane + 256 * r;
        int b = idx >> 5;
        int f0 = idx & 31;
        const float* zb = &lds[wv][b * HLEN];
        float4 s = {0.f, 0.f, 0.f, 0.f};
#pragma unroll
        for (int h = 0; h < HLEN; h++) {
            float zv = zb[h];
            s.x += zv * wk[h * G1 + f0 + 0];
            s.y += zv * wk[h * G1 + f0 + 1];
            s.z += zv * wk[h * G1 + f0 + 2];
            s.w += zv * wk[h * G1 + f0 + 3];
        }
        float4 cur = *(const float4*)(op + idx);
        cur.x += s.x; cur.y += s.y; cur.z += s.z; cur.w += s.w;
        *(float4*)(op + idx) = cur;
    }
}

// ---------------- FC: logits[b,c] = sum_{n,f} relu(out + cb) * fc_w ----------------
// Block: 1024 threads = 16 waves; thread t -> (b,f) = (t>>5, t&31).
// Each block handles a contiguous node range; atomicAdd partials into logits.
__global__ __launch_bounds__(1024) void fc_kernel(const float* __restrict__ out,
                                                  const float* __restrict__ conv_b,
                                                  const float* __restrict__ fc_w,
                                                  float* __restrict__ logits) {
    int t = threadIdx.x;
    int lane = t & 63;
    int b = t >> 5;        // 0..31
    int f = t & 31;        // 0..31
    float cbf = conv_b[f];

    const int nodes_per = (N_NODES + gridDim.x - 1) / gridDim.x;
    int n0 = blockIdx.x * nodes_per;
    int n1 = n0 + nodes_per;
    if (n1 > N_NODES) n1 = N_NODES;

    float acc[NCLS];
#pragma unroll
    for (int c = 0; c < NCLS; c++) acc[c] = 0.f;

    for (int n = n0; n < n1; n++) {
        float h = out[(size_t)n * BG + t] + cbf;
        h = h > 0.f ? h : 0.f;
        const float* wp = fc_w + (size_t)n * G1 + f;
#pragma unroll
        for (int c = 0; c < NCLS; c++)
            acc[c] += h * wp[(size_t)c * (N_NODES * G1)];
    }
#pragma unroll
    for (int c = 0; c < NCLS; c++) {
        float v = acc[c];
        v += __shfl_xor(v, 1);
        v += __shfl_xor(v, 2);
        v += __shfl_xor(v, 4);
        v += __shfl_xor(v, 8);
        v += __shfl_xor(v, 16);
        if ((lane & 31) == 0) atomicAdd(&logits[b * NCLS + c], v);
    }
}

__global__ void softmax_kernel(const float* __restrict__ logits,
                               const float* __restrict__ fc_b,
                               float* __restrict__ out) {
    int b = threadIdx.x;
    if (b < BATCH) {
        float v[NCLS];
        float m = -1e30f;
#pragma unroll
        for (int c = 0; c < NCLS; c++) {
            v[c] = logits[b * NCLS + c] + fc_b[c];
            m = fmaxf(m, v[c]);
        }
        float s = 0.f;
#pragma unroll
        for (int c = 0; c < NCLS; c++) s += expf(v[c] - m);
        float ls = logf(s);
#pragma unroll
        for (int c = 0; c < NCLS; c++) out[b * NCLS + c] = v[c] - m - ls;
    }
}

extern "C" void kernel_launch(void* const* d_in, const int* in_sizes, int n_in,
                              void* d_out, int out_size, void* d_ws, size_t ws_size,
                              hipStream_t stream) {
    const float* x      = (const float*)d_in[0];
    const int*   ei     = (const int*)d_in[1];
    const float* conv_w = (const float*)d_in[2];
    const float* conv_b = (const float*)d_in[3];
    const float* fc_w   = (const float*)d_in[4];
    const float* fc_b   = (const float*)d_in[5];
    float* outp = (float*)d_out;

    const int* row = ei;
    const int* col = ei + N_EDGES;

    char* ws = (char*)d_ws;
    size_t off = 0;
    auto alloc = [&](size_t bytes) -> void* {
        void* p = ws + off;
        off = (off + bytes + 255) & ~(size_t)255;
        return p;
    };
    float* buf0     = (float*)alloc(sizeof(float) * (size_t)N_NODES * BH);
    float* buf1     = (float*)alloc(sizeof(float) * (size_t)N_NODES * BH);
    float* outacc   = (float*)alloc(sizeof(float) * (size_t)N_NODES * BG);
    int*   cnt      = (int*)alloc(sizeof(int) * N_NODES);
    float* dinv     = (float*)alloc(sizeof(float) * N_NODES);
    int*   rowstart = (int*)alloc(sizeof(int) * (N_NODES + 1));
    int*   cursor   = (int*)alloc(sizeof(int) * N_NODES);
    int*   csr_col  = (int*)alloc(sizeof(int) * N_EDGES);
    float* csr_norm = (float*)alloc(sizeof(float) * N_EDGES);
    float* logits   = (float*)alloc(sizeof(float) * BATCH * NCLS);

    hipMemsetAsync(cnt, 0, sizeof(int) * N_NODES, stream);
    hipMemsetAsync(cursor, 0, sizeof(int) * N_NODES, stream);
    hipMemsetAsync(logits, 0, sizeof(float) * BATCH * NCLS, stream);

    deg_kernel<<<(N_EDGES + 255) / 256, 256, 0, stream>>>(row, cnt);
    dinv_kernel<<<(N_NODES + 255) / 256, 256, 0, stream>>>(cnt, dinv);
    scan_kernel<<<1, 1024, 0, stream>>>(cnt, rowstart);
    scatter_kernel<<<(N_EDGES + 255) / 256, 256, 0, stream>>>(row, col, dinv, rowstart,
                                                              cursor, csr_col, csr_norm);
    fft_kernel<<<(N_NODES * BATCH + 255) / 256, 256, 0, stream>>>(x, buf0);

    // k = 0: out = T0 @ W0
    k0_kernel<<<N_NODES / 4, 256, 0, stream>>>(buf0, outacc, conv_w);
    // k = 1: T1 = Lt @ T0 ; out += T1 @ W1
    prop_kernel<<<N_NODES / 4, 256, 0, stream>>>(buf0, buf0, buf1, outacc, rowstart,
                                                 csr_col, csr_norm, conv_w + 1 * BH,
                                                 1.0f, 0.0f);
    float* zprev = buf0;
    float* zcur  = buf1;
    for (int k = 2; k < KORD; k++) {
        // T_k = 2 Lt T_{k-1} - T_{k-2}  (written over zprev's buffer)
        prop_kernel<<<N_NODES / 4, 256, 0, stream>>>(zcur, zprev, zprev, outacc, rowstart,
                                                     csr_col, csr_norm, conv_w + (size_t)k * BH,
                                                     2.0f, 1.0f);
        float* tmp = zprev; zprev = zcur; zcur = tmp;
    }

    fc_kernel<<<250, 1024, 0, stream>>>(outacc, conv_b, fc_w, logits);
    softmax_kernel<<<1, 64, 0, stream>>>(logits, fc_b, outp);
}